// Round 11
// baseline (310.342 us; speedup 1.0000x reference)
//
#include <hip/hip_runtime.h>
#include <math.h>

#define DIMX 1024
#define QKD  128
#define HIDD 2048
#define BATCH 4
#define SEQ  2048

typedef __bf16 bf16;
typedef __bf16 bf16x8 __attribute__((ext_vector_type(8)));
typedef __bf16 bf16x4v __attribute__((ext_vector_type(4)));
typedef float f32x4 __attribute__((ext_vector_type(4)));

__device__ __forceinline__ float siluf(float v) { return v / (1.f + expf(-v)); }
__device__ __forceinline__ void splitf(float x, bf16& h, bf16& l) {
    h = (bf16)x;
    l = (bf16)(x - (float)h);
}
__device__ __forceinline__ f32x4 mfma16(bf16x8 a, bf16x8 b, f32x4 c) {
    return __builtin_amdgcn_mfma_f32_16x16x32_bf16(a, b, c, 0, 0, 0);
}

typedef __attribute__((address_space(1))) const void cg_void;
typedef __attribute__((address_space(3))) void lds_void_t;
__device__ __forceinline__ void gload16(const bf16* g, bf16* l) {
    __builtin_amdgcn_global_load_lds((cg_void*)g, (lds_void_t*)l, 16, 0, 0);
}

template<int N> __device__ __forceinline__ void wait_vm() {
    if constexpr (N == 0)  asm volatile("s_waitcnt vmcnt(0)" ::: "memory");
    if constexpr (N == 3)  asm volatile("s_waitcnt vmcnt(3)" ::: "memory");
    if constexpr (N == 6)  asm volatile("s_waitcnt vmcnt(6)" ::: "memory");
}

#define SB0 __builtin_amdgcn_sched_barrier(0)

// -------------------- LayerNorm -> split bf16 hi/lo --------------------
__global__ __launch_bounds__(256) void ln_split(const float* __restrict__ x,
                                                const float* __restrict__ scale,
                                                const float* __restrict__ bias,
                                                bf16* __restrict__ xh,
                                                bf16* __restrict__ xl) {
    const int row = blockIdx.x;
    const float4 v = reinterpret_cast<const float4*>(x + (size_t)row * DIMX)[threadIdx.x];
    float s  = v.x + v.y + v.z + v.w;
    float ss = v.x * v.x + v.y * v.y + v.z * v.z + v.w * v.w;
    #pragma unroll
    for (int off = 32; off; off >>= 1) {
        s  += __shfl_down(s, off);
        ss += __shfl_down(ss, off);
    }
    __shared__ float ls[4], lss[4];
    const int wid = threadIdx.x >> 6, lane = threadIdx.x & 63;
    if (lane == 0) { ls[wid] = s; lss[wid] = ss; }
    __syncthreads();
    if (threadIdx.x == 0) {
        float a = ls[0] + ls[1] + ls[2] + ls[3];
        float b = lss[0] + lss[1] + lss[2] + lss[3];
        float mu  = a / DIMX;
        float var = b / DIMX - mu * mu;
        ls[0]  = mu;
        lss[0] = rsqrtf(var + 1e-5f);
    }
    __syncthreads();
    const float mu = ls[0], rs = lss[0];
    const float4 sc = reinterpret_cast<const float4*>(scale)[threadIdx.x];
    const float4 bi = reinterpret_cast<const float4*>(bias)[threadIdx.x];
    float o[4];
    o[0] = (v.x - mu) * rs * sc.x + bi.x;
    o[1] = (v.y - mu) * rs * sc.y + bi.y;
    o[2] = (v.z - mu) * rs * sc.z + bi.z;
    o[3] = (v.w - mu) * rs * sc.w + bi.w;
    bf16x4v h, l;
    #pragma unroll
    for (int i = 0; i < 4; ++i) { bf16 hh, ll; splitf(o[i], hh, ll); h[i] = hh; l[i] = ll; }
    *reinterpret_cast<bf16x4v*>(xh + (size_t)row * DIMX + threadIdx.x * 4) = h;
    *reinterpret_cast<bf16x4v*>(xl + (size_t)row * DIMX + threadIdx.x * 4) = l;
}

// ------------- transpose + split: W [K][N] fp32 -> T[N][K] bf16 hi(/lo) -------------
__global__ __launch_bounds__(256) void wsplitT(const float* __restrict__ W, int K, int N,
                                               bf16* __restrict__ Th, bf16* __restrict__ Tl) {
    __shared__ float tile[32][33];
    const int bx = blockIdx.x * 32;   // N dir
    const int by = blockIdx.y * 32;   // K dir
    const int tx = threadIdx.x & 31, ty = threadIdx.x >> 5;
    #pragma unroll
    for (int r = 0; r < 32; r += 8)
        tile[ty + r][tx] = W[(size_t)(by + ty + r) * N + bx + tx];
    __syncthreads();
    #pragma unroll
    for (int r = 0; r < 32; r += 8) {
        const float v = tile[tx][ty + r];
        bf16 h, l; splitf(v, h, l);
        Th[(size_t)(bx + ty + r) * K + by + tx] = h;
        if (Tl) Tl[(size_t)(bx + ty + r) * K + by + tx] = l;
    }
}

// =====================================================================
// gmm6: LDS-ratio-tuned ring GEMM.  BM=128, BN=256, BK=32, 256 threads
// (4 waves 2Mx2N, per-wave 64x128 -> FLOP/LDS-byte 42.7 vs 32 at 64x64),
// 3-deep LDS ring (72 KB -> 2 blk/CU with launch_bounds(256,2)),
// single barrier per K-step (round-9/10 proven semantics):
//   [wait_vm(6|0); barrier; ds_read(t); lgkm0; stage(t+2); MFMA(t)]
// WAR: stage(t+2) overwrites buf[(t-1)%3]; all iter-(t-1) reads completed
// before any wave passed barrier t (lgkm0 precedes arrival).  RAW: at
// iter-t top outstanding = tiles {t,t+1} (12 loads); wait_vm(6) retires
// tile t; tail 0.  XCD-contiguous remap (bijective; nwg%8==0).
// EPI 0 (hid): s=silu(acc+e0[n]); n<HIDD -> O[n][m] (vT) else G[n-HIDD][m]
// EPI 3 (av):  y = acc * G[n][m] -> O[m][n] bf16
// EPI 4 (out): F[m][n] = acc + e0[n]  fp32
// =====================================================================
template<int EPI>
__global__ __launch_bounds__(256, 2) void gmm6(
    const bf16* __restrict__ A, int lda, long long sA,
    const bf16* __restrict__ B, int ldb, long long sB,
    bf16* __restrict__ O, int ldo, long long sO,
    bf16* __restrict__ G, int ldg, long long sG,
    float* __restrict__ F, int ldf,
    const float* __restrict__ e0,
    int K) {

    constexpr int BM = 128, BN = 256, BK = 32;
    constexpr int AE = BM * BK;            // 4096 elems (8 KB)
    constexpr int BE = BN * BK;            // 8192 elems (16 KB)
    constexpr int TE = AE + BE;            // 12288 elems (24 KB)
    constexpr int MI = 4, NI = 8;          // wave tile 64 x 128

    __shared__ __align__(16) bf16 lds[3 * TE];   // 72 KB

    // ---- XCD-contiguous remap (bijective; caller guarantees nwg%8==0) ----
    const int gx = gridDim.x;
    const int nwg = gx * gridDim.y;
    const int lin = blockIdx.x + gx * blockIdx.y;
    const int qq = nwg >> 3;
    const int nl = (lin & 7) * qq + (lin >> 3);
    const int bm = (nl / gx) * BM, bn = (nl % gx) * BN;

    const int z = blockIdx.z;
    A += (size_t)sA * z;
    B += (size_t)sB * z;
    bf16* Oz = O ? O + (size_t)sO * z : nullptr;
    bf16* Gz = G ? G + (size_t)sG * z : nullptr;

    const int tid = threadIdx.x;
    const int l = tid & 63, w = tid >> 6;
    const int wr = w >> 1, wc = w & 1;     // 2M x 2N wave grid
    const int lr = l & 15, ls4 = l >> 4;

    // ---- staging source pointers (slot-XOR pre-swizzled global; LDS linear) ----
    // A: 512 load-slots (128 rows x 4), thread handles flat = {tid, 256+tid}
    const bf16* aptr[2];
    #pragma unroll
    for (int c = 0; c < 2; ++c) {
        const int flat = c * 256 + tid;
        const int row = flat >> 2;
        const int slot = (flat & 3) ^ ((row >> 1) & 3);
        aptr[c] = A + (size_t)(bm + row) * lda + slot * 8;
    }
    // B: 1024 load-slots (256 rows x 4), thread handles flat = c*256+tid, c=0..3
    const bf16* bptr[4];
    #pragma unroll
    for (int c = 0; c < 4; ++c) {
        const int flat = c * 256 + tid;
        const int row = flat >> 2;
        const int slot = (flat & 3) ^ ((row >> 1) & 3);
        bptr[c] = B + (size_t)(bn + row) * ldb + slot * 8;
    }

    // ---- fragment ds_read offsets (matching XOR swizzle) ----
    int aoff[MI], boff[NI];
    #pragma unroll
    for (int i = 0; i < MI; ++i) {
        const int row = wr * 64 + i * 16 + lr;
        aoff[i] = row * BK + (ls4 ^ ((row >> 1) & 3)) * 8;
    }
    #pragma unroll
    for (int j = 0; j < NI; ++j) {
        const int row = wc * 128 + j * 16 + lr;
        boff[j] = row * BK + (ls4 ^ ((row >> 1) & 3)) * 8;
    }

    const int NT = K / BK;
    f32x4 acc[MI][NI] = {};

    auto stage = [&](int tile) {
        bf16* tb = lds + (tile % 3) * TE;
        gload16(aptr[0] + (size_t)tile * BK, tb + w * 512);
        gload16(aptr[1] + (size_t)tile * BK, tb + 2048 + w * 512);
        bf16* bb = tb + AE;
        gload16(bptr[0] + (size_t)tile * BK, bb + w * 512);
        gload16(bptr[1] + (size_t)tile * BK, bb + 2048 + w * 512);
        gload16(bptr[2] + (size_t)tile * BK, bb + 4096 + w * 512);
        gload16(bptr[3] + (size_t)tile * BK, bb + 6144 + w * 512);
    };

    stage(0); SB0;
    stage(1); SB0;

    for (int t = 0; t < NT; ++t) {
        if (t + 1 < NT) wait_vm<6>();      // retire tile t; t+1 stays in flight
        else            wait_vm<0>();
        __builtin_amdgcn_s_barrier();      // all waves' tile-t landed
        SB0;

        const bf16* tb = lds + (t % 3) * TE;
        const bf16* bb = tb + AE;
        bf16x8 afr[MI], bfr[NI];
        #pragma unroll
        for (int j = 0; j < NI; ++j)
            bfr[j] = *reinterpret_cast<const bf16x8*>(&bb[boff[j]]);
        #pragma unroll
        for (int i = 0; i < MI; ++i)
            afr[i] = *reinterpret_cast<const bf16x8*>(&tb[aoff[i]]);
        asm volatile("s_waitcnt lgkmcnt(0)" ::: "memory");
        SB0;
        if (t + 2 < NT) { stage(t + 2); }  // overwrites buf[(t-1)%3]: safe
        SB0;
        __builtin_amdgcn_s_setprio(1);
        #pragma unroll
        for (int i = 0; i < MI; ++i)
            #pragma unroll
            for (int j = 0; j < NI; ++j)
                acc[i][j] = mfma16(afr[i], bfr[j], acc[i][j]);
        __builtin_amdgcn_s_setprio(0);
        SB0;
    }

    // ---- epilogue ----
    #pragma unroll
    for (int i = 0; i < MI; ++i) {
        const int mf = bm + wr * 64 + i * 16 + ls4 * 4;   // rows mf..mf+3
        #pragma unroll
        for (int j = 0; j < NI; ++j) {
            const int nn = bn + wc * 128 + j * 16 + lr;
            const f32x4 a = acc[i][j];
            if constexpr (EPI == 0) {
                float s[4];
                #pragma unroll
                for (int r = 0; r < 4; ++r) s[r] = siluf(a[r] + e0[nn]);
                bf16x4v h;
                #pragma unroll
                for (int r = 0; r < 4; ++r) h[r] = (bf16)s[r];
                if (nn < HIDD)
                    *reinterpret_cast<bf16x4v*>(&Oz[(size_t)nn * ldo + mf]) = h;
                else
                    *reinterpret_cast<bf16x4v*>(&Gz[(size_t)(nn - HIDD) * ldg + mf]) = h;
            } else if constexpr (EPI == 3) {
                const bf16x4v g4 = *reinterpret_cast<const bf16x4v*>(&Gz[(size_t)nn * ldg + mf]);
                #pragma unroll
                for (int r = 0; r < 4; ++r)
                    Oz[(size_t)(mf + r) * ldo + nn] = (bf16)(a[r] * (float)g4[r]);
            } else {
                #pragma unroll
                for (int r = 0; r < 4; ++r)
                    F[(size_t)(mf + r) * ldf + nn] = a[r] + e0[nn];
            }
        }
    }
}

// ---------------- round-4 2-barrier kernel: qk (EPI1) and sim (EPI2) ----------
template<int EPI, bool SPLIT, int MI, int NI>
__global__ __launch_bounds__(256) void gmm(
    const bf16* __restrict__ Ah, const bf16* __restrict__ Al, int lda, long long sA,
    const bf16* __restrict__ Bh, const bf16* __restrict__ Bl, int ldb, long long sB,
    bf16* __restrict__ O, int ldo, long long sO,
    bf16* __restrict__ O2, bf16* __restrict__ O3, bf16* __restrict__ O4,
    const float* __restrict__ e0, const float* __restrict__ e1, const float* __restrict__ e2,
    int K, float scale) {

    constexpr int TM = MI * 32, TN = NI * 32;
    constexpr int CHA = TM / 64, CHB = TN / 64;
    __shared__ __align__(16) bf16 As[TM * 32];
    __shared__ __align__(16) bf16 Bs[TN * 32];

    const int z = blockIdx.z;
    Ah += (size_t)sA * z;
    if (SPLIT) Al += (size_t)sA * z;
    Bh += (size_t)sB * z;
    if (SPLIT) Bl += (size_t)sB * z;
    if (O) O += (size_t)sO * z;

    const int t = threadIdx.x;
    const int l = t & 63, w = t >> 6;
    const int wr = w >> 1, wc = w & 1;
    const int lr = l & 15, ls = l >> 4;
    const int bm = blockIdx.y * TM, bn = blockIdx.x * TN;

    f32x4 acc[MI][NI] = {};
    const int KT = SPLIT ? 3 * K : K;

    for (int k0 = 0; k0 < KT; k0 += 32) {
        const bf16 *pA, *pB;
        int kin;
        if constexpr (SPLIT) {
            if (k0 < K)          { pA = Ah; pB = Bh; kin = k0; }
            else if (k0 < 2 * K) { pA = Al; pB = Bh; kin = k0 - K; }
            else                 { pA = Ah; pB = Bl; kin = k0 - 2 * K; }
        } else { pA = Ah; pB = Bh; kin = k0; }

        #pragma unroll
        for (int c = 0; c < CHA; ++c) {
            const int idx = c * 256 + w * 64 + l;
            const int row = idx >> 2;
            const int sg = (idx & 3) ^ ((row >> 1) & 3);
            gload16(pA + (size_t)(bm + row) * lda + kin + sg * 8,
                    As + (size_t)(c * 256 + w * 64) * 8);
        }
        #pragma unroll
        for (int c = 0; c < CHB; ++c) {
            const int idx = c * 256 + w * 64 + l;
            const int row = idx >> 2;
            const int sg = (idx & 3) ^ ((row >> 1) & 3);
            gload16(pB + (size_t)(bn + row) * ldb + kin + sg * 8,
                    Bs + (size_t)(c * 256 + w * 64) * 8);
        }
        __syncthreads();

        bf16x8 bfr[NI];
        #pragma unroll
        for (int j = 0; j < NI; ++j) {
            const int row = wc * (NI * 16) + j * 16 + lr;
            const int sl = ls ^ ((row >> 1) & 3);
            bfr[j] = *reinterpret_cast<const bf16x8*>(&Bs[row * 32 + sl * 8]);
        }
        #pragma unroll
        for (int i = 0; i < MI; ++i) {
            const int row = wr * (MI * 16) + i * 16 + lr;
            const int sl = ls ^ ((row >> 1) & 3);
            const bf16x8 af = *reinterpret_cast<const bf16x8*>(&As[row * 32 + sl * 8]);
            #pragma unroll
            for (int j = 0; j < NI; ++j)
                acc[i][j] = mfma16(af, bfr[j], acc[i][j]);
        }
        __syncthreads();
    }

    #pragma unroll
    for (int i = 0; i < MI; ++i) {
        const int mf = bm + wr * (MI * 16) + i * 16 + ls * 4;
        #pragma unroll
        for (int j = 0; j < NI; ++j) {
            const int nn = bn + wc * (NI * 16) + j * 16 + lr;
            const f32x4 a = acc[i][j];
            if constexpr (EPI == 1) {
                #pragma unroll
                for (int r = 0; r < 4; ++r) {
                    const float s = siluf(a[r] + e0[nn]);
                    const float q = s * e1[nn] + e2[nn];
                    const float k = s * e1[QKD + nn] + e2[QKD + nn];
                    bf16 h, lo;
                    splitf(q, h, lo);
                    O[(size_t)(mf + r) * ldo + nn] = h;  O2[(size_t)(mf + r) * ldo + nn] = lo;
                    splitf(k, h, lo);
                    O3[(size_t)(mf + r) * ldo + nn] = h; O4[(size_t)(mf + r) * ldo + nn] = lo;
                }
            } else if constexpr (EPI == 2) {
                #pragma unroll
                for (int r = 0; r < 4; ++r) {
                    const float tv = a[r] * scale;
                    const float p = tv > 0.f ? tv * tv : 0.f;
                    O[(size_t)(mf + r) * ldo + nn] = (bf16)p;
                }
            }
        }
    }
}

extern "C" void kernel_launch(void* const* d_in, const int* in_sizes, int n_in,
                              void* d_out, int out_size, void* d_ws, size_t ws_size,
                              hipStream_t stream) {
    const float* x        = (const float*)d_in[0];
    const float* ln_scale = (const float*)d_in[1];
    const float* ln_bias  = (const float*)d_in[2];
    const float* W_hidden = (const float*)d_in[3];
    const float* b_hidden = (const float*)d_in[4];
    const float* W_qk     = (const float*)d_in[5];
    const float* b_qk     = (const float*)d_in[6];
    const float* os_w     = (const float*)d_in[7];
    const float* os_b     = (const float*)d_in[8];
    const float* W_out    = (const float*)d_in[9];
    const float* b_out    = (const float*)d_in[10];
    float* out = (float*)d_out;

    // ---- weight prep area ----
    char* p = (char*)d_ws;
    bf16* WhTh  = (bf16*)p; p += (size_t)4096 * 1024 * 2;   // [4096][1024]
    bf16* WqkTh = (bf16*)p; p += (size_t)128 * 1024 * 2;    // [128][1024] hi
    bf16* WqkTl = (bf16*)p; p += (size_t)128 * 1024 * 2;    // lo
    bf16* WoTh  = (bf16*)p; p += (size_t)1024 * 2048 * 2;   // [1024][2048]

    wsplitT<<<dim3(4096 / 32, 1024 / 32), 256, 0, stream>>>(W_hidden, 1024, 4096, WhTh, nullptr);
    wsplitT<<<dim3(128 / 32, 1024 / 32), 256, 0, stream>>>(W_qk, 1024, 128, WqkTh, WqkTl);
    wsplitT<<<dim3(1024 / 32, 2048 / 32), 256, 0, stream>>>(W_out, 2048, 1024, WoTh, nullptr);

    const size_t used = (size_t)(p - (char*)d_ws);
    const size_t qkB   = (size_t)4 * 8192 * 128 * 2;
    const size_t vTB   = (size_t)2048 * 8192 * 2;
    const size_t gateB = (size_t)2048 * 8192 * 2;
    const size_t attnB = (size_t)4 * 2048 * 2048 * 2;
    const size_t yB    = (size_t)8192 * 2048 * 2;
    const bool allb = (ws_size >= used + qkB + vTB + gateB + attnB + yB + (1u << 20));

    if (allb) {
        bf16* xh = (bf16*)out;                      // d_out doubles as xn hi/lo
        bf16* xl = xh + (size_t)8192 * 1024;
        bf16* qh   = (bf16*)p; p += (size_t)8192 * 128 * 2;
        bf16* ql   = (bf16*)p; p += (size_t)8192 * 128 * 2;
        bf16* kh   = (bf16*)p; p += (size_t)8192 * 128 * 2;
        bf16* kl   = (bf16*)p; p += (size_t)8192 * 128 * 2;
        bf16* vT   = (bf16*)p; p += vTB;            // [2048][8192]
        bf16* gateT= (bf16*)p; p += gateB;          // [2048][8192]
        bf16* attn = (bf16*)p; p += attnB;          // [4][2048][2048]
        bf16* y    = (bf16*)p; p += yB;             // [8192][2048]

        ln_split<<<8192, 256, 0, stream>>>(x, ln_scale, ln_bias, xh, xl);

        // hid: [8192 x 4096] -> vT + gateT   (grid 16x64 = 1024 blocks)
        gmm6<0><<<dim3(4096 / 256, 8192 / 128), 256, 0, stream>>>(
            xh, 1024, 0, WhTh, 1024, 0,
            vT, 8192, 0, gateT, 8192, 0,
            nullptr, 0, b_hidden, 1024);

        // qk (split): [8192 x 128] -> q,k hi/lo
        gmm<1, true, 2, 2><<<dim3(128 / 64, 8192 / 64), 256, 0, stream>>>(
            xh, xl, 1024, 0, WqkTh, WqkTl, 1024, 0,
            qh, 128, 0, ql, kh, kl,
            b_qk, os_w, os_b, 1024, 0.f);

        // sim (split): per-batch [2048 x 2048]
        gmm<2, true, 4, 4><<<dim3(16, 16, 4), 256, 0, stream>>>(
            qh, ql, 128, (long long)2048 * 128, kh, kl, 128, (long long)2048 * 128,
            attn, 2048, (long long)2048 * 2048, nullptr, nullptr, nullptr,
            nullptr, nullptr, nullptr, 128, 1.0f / SEQ);

        // av: [2048 x 2048] per batch, * gate  (grid 8x16x4)
        gmm6<3><<<dim3(2048 / 256, 2048 / 128, 4), 256, 0, stream>>>(
            attn, 2048, (long long)2048 * 2048, vT, 8192, 2048,
            y, 2048, (long long)2048 * 2048, gateT, 8192, 2048,
            nullptr, 0, nullptr, 2048);

        // out: [8192 x 1024] fp32 -> d_out  (grid 4x64 = 256 blocks)
        gmm6<4><<<dim3(1024 / 256, 8192 / 128), 256, 0, stream>>>(
            y, 2048, 0, WoTh, 2048, 0,
            nullptr, 0, 0, nullptr, 0, 0,
            out, 1024, b_out, 2048);
    } else {
        // ---------------- per-batch fallback ----------------
        bf16* xh = (bf16*)p; p += (size_t)8192 * 1024 * 2;
        bf16* xl = (bf16*)p; p += (size_t)8192 * 1024 * 2;
        bf16* qh   = (bf16*)p; p += (size_t)2048 * 128 * 2;
        bf16* ql   = (bf16*)p; p += (size_t)2048 * 128 * 2;
        bf16* kh   = (bf16*)p; p += (size_t)2048 * 128 * 2;
        bf16* kl   = (bf16*)p; p += (size_t)2048 * 128 * 2;
        bf16* vT   = (bf16*)p; p += (size_t)2048 * 2048 * 2;
        bf16* gateT= (bf16*)p; p += (size_t)2048 * 2048 * 2;
        bf16* attn = (bf16*)p; p += (size_t)2048 * 2048 * 2;
        bf16* y    = (bf16*)p; p += (size_t)2048 * 2048 * 2;

        ln_split<<<8192, 256, 0, stream>>>(x, ln_scale, ln_bias, xh, xl);

        for (int b = 0; b < BATCH; ++b) {
            const bf16* xhb = xh + (size_t)b * 2048 * 1024;
            const bf16* xlb = xl + (size_t)b * 2048 * 1024;

            gmm6<0><<<dim3(4096 / 256, 2048 / 128), 256, 0, stream>>>(
                xhb, 1024, 0, WhTh, 1024, 0,
                vT, 2048, 0, gateT, 2048, 0,
                nullptr, 0, b_hidden, 1024);

            gmm<1, true, 2, 2><<<dim3(128 / 64, 2048 / 64), 256, 0, stream>>>(
                xhb, xlb, 1024, 0, WqkTh, WqkTl, 1024, 0,
                qh, 128, 0, ql, kh, kl,
                b_qk, os_w, os_b, 1024, 0.f);

            gmm<2, true, 4, 4><<<dim3(16, 16, 1), 256, 0, stream>>>(
                qh, ql, 128, 0, kh, kl, 128, 0,
                attn, 2048, 0, nullptr, nullptr, nullptr,
                nullptr, nullptr, nullptr, 128, 1.0f / SEQ);

            gmm6<3><<<dim3(2048 / 256, 2048 / 128, 1), 256, 0, stream>>>(
                attn, 2048, 0, vT, 2048, 0,
                y, 2048, 0, gateT, 2048, 0,
                nullptr, 0, nullptr, 2048);

            gmm6<4><<<dim3(1024 / 256, 2048 / 128), 256, 0, stream>>>(
                y, 2048, 0, WoTh, 2048, 0,
                nullptr, 0, 0, nullptr, 0, 0,
                out + (size_t)b * 2048 * 1024, 1024, b_out, 2048);
        }
    }
}

// Round 12
// 293.980 us; speedup vs baseline: 1.0557x; 1.0557x over previous
//
#include <hip/hip_runtime.h>
#include <math.h>

#define DIMX 1024
#define QKD  128
#define HIDD 2048
#define BATCH 4
#define SEQ  2048

typedef __bf16 bf16;
typedef __bf16 bf16x8 __attribute__((ext_vector_type(8)));
typedef __bf16 bf16x4v __attribute__((ext_vector_type(4)));
typedef float f32x4 __attribute__((ext_vector_type(4)));

__device__ __forceinline__ float siluf(float v) { return v / (1.f + expf(-v)); }
__device__ __forceinline__ void splitf(float x, bf16& h, bf16& l) {
    h = (bf16)x;
    l = (bf16)(x - (float)h);
}
__device__ __forceinline__ f32x4 mfma16(bf16x8 a, bf16x8 b, f32x4 c) {
    return __builtin_amdgcn_mfma_f32_16x16x32_bf16(a, b, c, 0, 0, 0);
}

typedef __attribute__((address_space(1))) const void cg_void;
typedef __attribute__((address_space(3))) void lds_void_t;
__device__ __forceinline__ void gload16(const bf16* g, bf16* l) {
    __builtin_amdgcn_global_load_lds((cg_void*)g, (lds_void_t*)l, 16, 0, 0);
}

#define SB0 __builtin_amdgcn_sched_barrier(0)

// -------------------- LayerNorm -> split bf16 hi/lo --------------------
__global__ __launch_bounds__(256) void ln_split(const float* __restrict__ x,
                                                const float* __restrict__ scale,
                                                const float* __restrict__ bias,
                                                bf16* __restrict__ xh,
                                                bf16* __restrict__ xl) {
    const int row = blockIdx.x;
    const float4 v = reinterpret_cast<const float4*>(x + (size_t)row * DIMX)[threadIdx.x];
    float s  = v.x + v.y + v.z + v.w;
    float ss = v.x * v.x + v.y * v.y + v.z * v.z + v.w * v.w;
    #pragma unroll
    for (int off = 32; off; off >>= 1) {
        s  += __shfl_down(s, off);
        ss += __shfl_down(ss, off);
    }
    __shared__ float ls[4], lss[4];
    const int wid = threadIdx.x >> 6, lane = threadIdx.x & 63;
    if (lane == 0) { ls[wid] = s; lss[wid] = ss; }
    __syncthreads();
    if (threadIdx.x == 0) {
        float a = ls[0] + ls[1] + ls[2] + ls[3];
        float b = lss[0] + lss[1] + lss[2] + lss[3];
        float mu  = a / DIMX;
        float var = b / DIMX - mu * mu;
        ls[0]  = mu;
        lss[0] = rsqrtf(var + 1e-5f);
    }
    __syncthreads();
    const float mu = ls[0], rs = lss[0];
    const float4 sc = reinterpret_cast<const float4*>(scale)[threadIdx.x];
    const float4 bi = reinterpret_cast<const float4*>(bias)[threadIdx.x];
    float o[4];
    o[0] = (v.x - mu) * rs * sc.x + bi.x;
    o[1] = (v.y - mu) * rs * sc.y + bi.y;
    o[2] = (v.z - mu) * rs * sc.z + bi.z;
    o[3] = (v.w - mu) * rs * sc.w + bi.w;
    bf16x4v h, l;
    #pragma unroll
    for (int i = 0; i < 4; ++i) { bf16 hh, ll; splitf(o[i], hh, ll); h[i] = hh; l[i] = ll; }
    *reinterpret_cast<bf16x4v*>(xh + (size_t)row * DIMX + threadIdx.x * 4) = h;
    *reinterpret_cast<bf16x4v*>(xl + (size_t)row * DIMX + threadIdx.x * 4) = l;
}

// ------------- transpose + split: W [K][N] fp32 -> T[N][K] bf16 hi(/lo) -------------
__global__ __launch_bounds__(256) void wsplitT(const float* __restrict__ W, int K, int N,
                                               bf16* __restrict__ Th, bf16* __restrict__ Tl) {
    __shared__ float tile[32][33];
    const int bx = blockIdx.x * 32;   // N dir
    const int by = blockIdx.y * 32;   // K dir
    const int tx = threadIdx.x & 31, ty = threadIdx.x >> 5;
    #pragma unroll
    for (int r = 0; r < 32; r += 8)
        tile[ty + r][tx] = W[(size_t)(by + ty + r) * N + bx + tx];
    __syncthreads();
    #pragma unroll
    for (int r = 0; r < 32; r += 8) {
        const float v = tile[tx][ty + r];
        bf16 h, l; splitf(v, h, l);
        Th[(size_t)(bx + ty + r) * K + by + tx] = h;
        if (Tl) Tl[(size_t)(bx + ty + r) * K + by + tx] = l;
    }
}

// =====================================================================
// gmm7: compiler-scheduled double-buffer GEMM.  BM x 256 tile, BK=64
// (2 proven 32-wide panels per buffer), 512 thr (8 waves 2Mx4N),
// ring-2 LDS (128 KB @ BM=256, 96 KB @ BM=128).  ONE __syncthreads per
// 64-K step: its vmcnt(0) drain waits exactly the needed tile (issued a
// full iteration earlier -> already landed); its lgkm drain + barrier
// give the WAR guarantee for stage(t+1) overwriting tile t-1.  No asm
// waits, no fences around reads/MFMA -- compiler emits fine-grained
// lgkmcnt interleave (m97-style).  Proven slot-XOR swizzle per panel.
// EPI 0 (hid): s=silu(acc+e0[n]); n<HIDD -> O[n][m] (vT) else G[n-HIDD][m]
// EPI 3 (av):  y = acc * G[n][m] -> O[m][n] bf16
// EPI 4 (out): F[m][n] = acc + e0[n]  fp32
// =====================================================================
template<int EPI, int BM>
__global__ __launch_bounds__(512) void gmm7(
    const bf16* __restrict__ A, int lda, long long sA,
    const bf16* __restrict__ B, int ldb, long long sB,
    bf16* __restrict__ O, int ldo, long long sO,
    bf16* __restrict__ G, int ldg, long long sG,
    float* __restrict__ F, int ldf,
    const float* __restrict__ e0,
    int K) {

    constexpr int BN = 256;
    constexpr int AE = BM * 32;            // elems per A panel
    constexpr int BE = BN * 32;            // elems per B panel
    constexpr int PE = AE + BE;            // elems per panel (A+B)
    constexpr int HALF = 2 * PE;           // elems per 64-K buffer
    constexpr int CHA = AE / (512 * 8);    // A gload16 per thread per panel
    constexpr int CHB = BE / (512 * 8);    // B gload16 per thread per panel
    constexpr int MI = BM / 32, NI = 4;    // wave tile (BM/2) x 64

    __shared__ __align__(16) bf16 lds[2 * HALF];

    // ---- XCD-contiguous remap (bijective; caller guarantees nwg%8==0) ----
    const int gx = gridDim.x;
    const int nwg = gx * gridDim.y;
    const int lin = blockIdx.x + gx * blockIdx.y;
    const int qq = nwg >> 3;
    const int nl = (lin & 7) * qq + (lin >> 3);
    const int bm = (nl / gx) * BM, bn = (nl % gx) * BN;

    const int z = blockIdx.z;
    A += (size_t)sA * z;
    B += (size_t)sB * z;
    bf16* Oz = O ? O + (size_t)sO * z : nullptr;
    bf16* Gz = G ? G + (size_t)sG * z : nullptr;

    const int tid = threadIdx.x;
    const int l = tid & 63, w = tid >> 6;
    const int wr = w >> 2, wc = w & 3;     // 2M x 4N wave grid
    const int lr = l & 15, ls4 = l >> 4;

    // ---- staging source pointers (proven slot-XOR on 32-wide panels) ----
    const bf16* aptr[CHA];
    #pragma unroll
    for (int c = 0; c < CHA; ++c) {
        const int flat = c * 512 + tid;
        const int row = flat >> 2;
        const int slot = (flat & 3) ^ ((row >> 1) & 3);
        aptr[c] = A + (size_t)(bm + row) * lda + slot * 8;
    }
    const bf16* bptr[CHB];
    #pragma unroll
    for (int c = 0; c < CHB; ++c) {
        const int flat = c * 512 + tid;
        const int row = flat >> 2;
        const int slot = (flat & 3) ^ ((row >> 1) & 3);
        bptr[c] = B + (size_t)(bn + row) * ldb + slot * 8;
    }

    // ---- fragment ds_read offsets within a panel (proven) ----
    int aoff[MI], boff[NI];
    #pragma unroll
    for (int i = 0; i < MI; ++i) {
        const int row = wr * (BM / 2) + i * 16 + lr;
        aoff[i] = row * 32 + (ls4 ^ ((row >> 1) & 3)) * 8;
    }
    #pragma unroll
    for (int j = 0; j < NI; ++j) {
        const int row = wc * 64 + j * 16 + lr;
        boff[j] = row * 32 + (ls4 ^ ((row >> 1) & 3)) * 8;
    }

    const int NT = K / 64;
    f32x4 acc[MI][NI] = {};

    // stage one 64-K tile (both panels) into buffer (t&1)
    auto stage64 = [&](int t) {
        bf16* bb = lds + (t & 1) * HALF;
        #pragma unroll
        for (int h = 0; h < 2; ++h) {
            bf16* pb = bb + h * PE;
            const size_t ko = (size_t)t * 64 + h * 32;
            #pragma unroll
            for (int c = 0; c < CHA; ++c)
                gload16(aptr[c] + ko, pb + (c * 512 + w * 64) * 8);
            #pragma unroll
            for (int c = 0; c < CHB; ++c)
                gload16(bptr[c] + ko, pb + AE + (c * 512 + w * 64) * 8);
        }
    };

    stage64(0);

    for (int t = 0; t < NT; ++t) {
        __syncthreads();            // drains vmcnt: tile t landed; WAR point
        if (t + 1 < NT) stage64(t + 1);
        SB0;                        // pin stage issue before the read/MFMA region

        const bf16* bb = lds + (t & 1) * HALF;
        #pragma unroll
        for (int h = 0; h < 2; ++h) {
            const bf16* pb = bb + h * PE;
            bf16x8 afr[MI], bfr[NI];
            #pragma unroll
            for (int j = 0; j < NI; ++j)
                bfr[j] = *reinterpret_cast<const bf16x8*>(&pb[AE + boff[j]]);
            #pragma unroll
            for (int i = 0; i < MI; ++i)
                afr[i] = *reinterpret_cast<const bf16x8*>(&pb[aoff[i]]);
            #pragma unroll
            for (int i = 0; i < MI; ++i)
                #pragma unroll
                for (int j = 0; j < NI; ++j)
                    acc[i][j] = mfma16(afr[i], bfr[j], acc[i][j]);
        }
    }

    // ---- epilogue ----
    #pragma unroll
    for (int i = 0; i < MI; ++i) {
        const int mf = bm + wr * (BM / 2) + i * 16 + ls4 * 4;   // rows mf..mf+3
        #pragma unroll
        for (int j = 0; j < NI; ++j) {
            const int nn = bn + wc * 64 + j * 16 + lr;
            const f32x4 a = acc[i][j];
            if constexpr (EPI == 0) {
                float s[4];
                #pragma unroll
                for (int r = 0; r < 4; ++r) s[r] = siluf(a[r] + e0[nn]);
                bf16x4v h;
                #pragma unroll
                for (int r = 0; r < 4; ++r) h[r] = (bf16)s[r];
                if (nn < HIDD)
                    *reinterpret_cast<bf16x4v*>(&Oz[(size_t)nn * ldo + mf]) = h;
                else
                    *reinterpret_cast<bf16x4v*>(&Gz[(size_t)(nn - HIDD) * ldg + mf]) = h;
            } else if constexpr (EPI == 3) {
                const bf16x4v g4 = *reinterpret_cast<const bf16x4v*>(&Gz[(size_t)nn * ldg + mf]);
                #pragma unroll
                for (int r = 0; r < 4; ++r)
                    Oz[(size_t)(mf + r) * ldo + nn] = (bf16)(a[r] * (float)g4[r]);
            } else {
                #pragma unroll
                for (int r = 0; r < 4; ++r)
                    F[(size_t)(mf + r) * ldf + nn] = a[r] + e0[nn];
            }
        }
    }
}

// ---------------- round-4 2-barrier kernel: qk (EPI1) and sim (EPI2) ----------
template<int EPI, bool SPLIT, int MI, int NI>
__global__ __launch_bounds__(256) void gmm(
    const bf16* __restrict__ Ah, const bf16* __restrict__ Al, int lda, long long sA,
    const bf16* __restrict__ Bh, const bf16* __restrict__ Bl, int ldb, long long sB,
    bf16* __restrict__ O, int ldo, long long sO,
    bf16* __restrict__ O2, bf16* __restrict__ O3, bf16* __restrict__ O4,
    const float* __restrict__ e0, const float* __restrict__ e1, const float* __restrict__ e2,
    int K, float scale) {

    constexpr int TM = MI * 32, TN = NI * 32;
    constexpr int CHA = TM / 64, CHB = TN / 64;
    __shared__ __align__(16) bf16 As[TM * 32];
    __shared__ __align__(16) bf16 Bs[TN * 32];

    const int z = blockIdx.z;
    Ah += (size_t)sA * z;
    if (SPLIT) Al += (size_t)sA * z;
    Bh += (size_t)sB * z;
    if (SPLIT) Bl += (size_t)sB * z;
    if (O) O += (size_t)sO * z;

    const int t = threadIdx.x;
    const int l = t & 63, w = t >> 6;
    const int wr = w >> 1, wc = w & 1;
    const int lr = l & 15, ls = l >> 4;
    const int bm = blockIdx.y * TM, bn = blockIdx.x * TN;

    f32x4 acc[MI][NI] = {};
    const int KT = SPLIT ? 3 * K : K;

    for (int k0 = 0; k0 < KT; k0 += 32) {
        const bf16 *pA, *pB;
        int kin;
        if constexpr (SPLIT) {
            if (k0 < K)          { pA = Ah; pB = Bh; kin = k0; }
            else if (k0 < 2 * K) { pA = Al; pB = Bh; kin = k0 - K; }
            else                 { pA = Ah; pB = Bl; kin = k0 - 2 * K; }
        } else { pA = Ah; pB = Bh; kin = k0; }

        #pragma unroll
        for (int c = 0; c < CHA; ++c) {
            const int idx = c * 256 + w * 64 + l;
            const int row = idx >> 2;
            const int sg = (idx & 3) ^ ((row >> 1) & 3);
            gload16(pA + (size_t)(bm + row) * lda + kin + sg * 8,
                    As + (size_t)(c * 256 + w * 64) * 8);
        }
        #pragma unroll
        for (int c = 0; c < CHB; ++c) {
            const int idx = c * 256 + w * 64 + l;
            const int row = idx >> 2;
            const int sg = (idx & 3) ^ ((row >> 1) & 3);
            gload16(pB + (size_t)(bn + row) * ldb + kin + sg * 8,
                    Bs + (size_t)(c * 256 + w * 64) * 8);
        }
        __syncthreads();

        bf16x8 bfr[NI];
        #pragma unroll
        for (int j = 0; j < NI; ++j) {
            const int row = wc * (NI * 16) + j * 16 + lr;
            const int sl = ls ^ ((row >> 1) & 3);
            bfr[j] = *reinterpret_cast<const bf16x8*>(&Bs[row * 32 + sl * 8]);
        }
        #pragma unroll
        for (int i = 0; i < MI; ++i) {
            const int row = wr * (MI * 16) + i * 16 + lr;
            const int sl = ls ^ ((row >> 1) & 3);
            const bf16x8 af = *reinterpret_cast<const bf16x8*>(&As[row * 32 + sl * 8]);
            #pragma unroll
            for (int j = 0; j < NI; ++j)
                acc[i][j] = mfma16(af, bfr[j], acc[i][j]);
        }
        __syncthreads();
    }

    #pragma unroll
    for (int i = 0; i < MI; ++i) {
        const int mf = bm + wr * (MI * 16) + i * 16 + ls * 4;
        #pragma unroll
        for (int j = 0; j < NI; ++j) {
            const int nn = bn + wc * (NI * 16) + j * 16 + lr;
            const f32x4 a = acc[i][j];
            if constexpr (EPI == 1) {
                #pragma unroll
                for (int r = 0; r < 4; ++r) {
                    const float s = siluf(a[r] + e0[nn]);
                    const float q = s * e1[nn] + e2[nn];
                    const float k = s * e1[QKD + nn] + e2[QKD + nn];
                    bf16 h, lo;
                    splitf(q, h, lo);
                    O[(size_t)(mf + r) * ldo + nn] = h;  O2[(size_t)(mf + r) * ldo + nn] = lo;
                    splitf(k, h, lo);
                    O3[(size_t)(mf + r) * ldo + nn] = h; O4[(size_t)(mf + r) * ldo + nn] = lo;
                }
            } else if constexpr (EPI == 2) {
                #pragma unroll
                for (int r = 0; r < 4; ++r) {
                    const float tv = a[r] * scale;
                    const float p = tv > 0.f ? tv * tv : 0.f;
                    O[(size_t)(mf + r) * ldo + nn] = (bf16)p;
                }
            }
        }
    }
}

extern "C" void kernel_launch(void* const* d_in, const int* in_sizes, int n_in,
                              void* d_out, int out_size, void* d_ws, size_t ws_size,
                              hipStream_t stream) {
    const float* x        = (const float*)d_in[0];
    const float* ln_scale = (const float*)d_in[1];
    const float* ln_bias  = (const float*)d_in[2];
    const float* W_hidden = (const float*)d_in[3];
    const float* b_hidden = (const float*)d_in[4];
    const float* W_qk     = (const float*)d_in[5];
    const float* b_qk     = (const float*)d_in[6];
    const float* os_w     = (const float*)d_in[7];
    const float* os_b     = (const float*)d_in[8];
    const float* W_out    = (const float*)d_in[9];
    const float* b_out    = (const float*)d_in[10];
    float* out = (float*)d_out;

    // ---- weight prep area ----
    char* p = (char*)d_ws;
    bf16* WhTh  = (bf16*)p; p += (size_t)4096 * 1024 * 2;   // [4096][1024]
    bf16* WqkTh = (bf16*)p; p += (size_t)128 * 1024 * 2;    // [128][1024] hi
    bf16* WqkTl = (bf16*)p; p += (size_t)128 * 1024 * 2;    // lo
    bf16* WoTh  = (bf16*)p; p += (size_t)1024 * 2048 * 2;   // [1024][2048]

    wsplitT<<<dim3(4096 / 32, 1024 / 32), 256, 0, stream>>>(W_hidden, 1024, 4096, WhTh, nullptr);
    wsplitT<<<dim3(128 / 32, 1024 / 32), 256, 0, stream>>>(W_qk, 1024, 128, WqkTh, WqkTl);
    wsplitT<<<dim3(1024 / 32, 2048 / 32), 256, 0, stream>>>(W_out, 2048, 1024, WoTh, nullptr);

    const size_t used = (size_t)(p - (char*)d_ws);
    const size_t qkB   = (size_t)4 * 8192 * 128 * 2;
    const size_t vTB   = (size_t)2048 * 8192 * 2;
    const size_t gateB = (size_t)2048 * 8192 * 2;
    const size_t attnB = (size_t)4 * 2048 * 2048 * 2;
    const size_t yB    = (size_t)8192 * 2048 * 2;
    const bool allb = (ws_size >= used + qkB + vTB + gateB + attnB + yB + (1u << 20));

    if (allb) {
        bf16* xh = (bf16*)out;                      // d_out doubles as xn hi/lo
        bf16* xl = xh + (size_t)8192 * 1024;
        bf16* qh   = (bf16*)p; p += (size_t)8192 * 128 * 2;
        bf16* ql   = (bf16*)p; p += (size_t)8192 * 128 * 2;
        bf16* kh   = (bf16*)p; p += (size_t)8192 * 128 * 2;
        bf16* kl   = (bf16*)p; p += (size_t)8192 * 128 * 2;
        bf16* vT   = (bf16*)p; p += vTB;            // [2048][8192]
        bf16* gateT= (bf16*)p; p += gateB;          // [2048][8192]
        bf16* attn = (bf16*)p; p += attnB;          // [4][2048][2048]
        bf16* y    = (bf16*)p; p += yB;             // [8192][2048]

        ln_split<<<8192, 256, 0, stream>>>(x, ln_scale, ln_bias, xh, xl);

        // hid: [8192 x 4096] -> vT + gateT   (grid 16x32 = 512 blocks)
        gmm7<0, 256><<<dim3(4096 / 256, 8192 / 256), 512, 0, stream>>>(
            xh, 1024, 0, WhTh, 1024, 0,
            vT, 8192, 0, gateT, 8192, 0,
            nullptr, 0, b_hidden, 1024);

        // qk (split): [8192 x 128] -> q,k hi/lo
        gmm<1, true, 2, 2><<<dim3(128 / 64, 8192 / 64), 256, 0, stream>>>(
            xh, xl, 1024, 0, WqkTh, WqkTl, 1024, 0,
            qh, 128, 0, ql, kh, kl,
            b_qk, os_w, os_b, 1024, 0.f);

        // sim (split): per-batch [2048 x 2048]
        gmm<2, true, 4, 4><<<dim3(16, 16, 4), 256, 0, stream>>>(
            qh, ql, 128, (long long)2048 * 128, kh, kl, 128, (long long)2048 * 128,
            attn, 2048, (long long)2048 * 2048, nullptr, nullptr, nullptr,
            nullptr, nullptr, nullptr, 128, 1.0f / SEQ);

        // av: [2048 x 2048] per batch, * gate  (grid 8x8x4)
        gmm7<3, 256><<<dim3(2048 / 256, 2048 / 256, 4), 512, 0, stream>>>(
            attn, 2048, (long long)2048 * 2048, vT, 8192, 2048,
            y, 2048, (long long)2048 * 2048, gateT, 8192, 2048,
            nullptr, 0, nullptr, 2048);

        // out: [8192 x 1024] fp32 -> d_out  (grid 4x64 = 256 blocks)
        gmm7<4, 128><<<dim3(1024 / 256, 8192 / 128), 512, 0, stream>>>(
            y, 2048, 0, WoTh, 2048, 0,
            nullptr, 0, 0, nullptr, 0, 0,
            out, 1024, b_out, 2048);
    } else {
        // ---------------- per-batch fallback ----------------
        bf16* xh = (bf16*)p; p += (size_t)8192 * 1024 * 2;
        bf16* xl = (bf16*)p; p += (size_t)8192 * 1024 * 2;
        bf16* qh   = (bf16*)p; p += (size_t)2048 * 128 * 2;
        bf16* ql   = (bf16*)p; p += (size_t)2048 * 128 * 2;
        bf16* kh   = (bf16*)p; p += (size_t)2048 * 128 * 2;
        bf16* kl   = (bf16*)p; p += (size_t)2048 * 128 * 2;
        bf16* vT   = (bf16*)p; p += (size_t)2048 * 2048 * 2;
        bf16* gateT= (bf16*)p; p += (size_t)2048 * 2048 * 2;
        bf16* attn = (bf16*)p; p += (size_t)2048 * 2048 * 2;
        bf16* y    = (bf16*)p; p += (size_t)2048 * 2048 * 2;

        ln_split<<<8192, 256, 0, stream>>>(x, ln_scale, ln_bias, xh, xl);

        for (int b = 0; b < BATCH; ++b) {
            const bf16* xhb = xh + (size_t)b * 2048 * 1024;
            const bf16* xlb = xl + (size_t)b * 2048 * 1024;

            gmm7<0, 256><<<dim3(4096 / 256, 2048 / 256), 512, 0, stream>>>(
                xhb, 1024, 0, WhTh, 1024, 0,
                vT, 2048, 0, gateT, 2048, 0,
                nullptr, 0, b_hidden, 1024);

            gmm<1, true, 2, 2><<<dim3(128 / 64, 2048 / 64), 256, 0, stream>>>(
                xhb, xlb, 1024, 0, WqkTh, WqkTl, 1024, 0,
                qh, 128, 0, ql, kh, kl,
                b_qk, os_w, os_b, 1024, 0.f);

            gmm<2, true, 4, 4><<<dim3(16, 16, 1), 256, 0, stream>>>(
                qh, ql, 128, 0, kh, kl, 128, 0,
                attn, 2048, 0, nullptr, nullptr, nullptr,
                nullptr, nullptr, nullptr, 128, 1.0f / SEQ);

            gmm7<3, 256><<<dim3(2048 / 256, 2048 / 256, 1), 512, 0, stream>>>(
                attn, 2048, 0, vT, 2048, 0,
                y, 2048, 0, gateT, 2048, 0,
                nullptr, 0, nullptr, 2048);

            gmm7<4, 128><<<dim3(1024 / 256, 2048 / 128), 512, 0, stream>>>(
                y, 2048, 0, WoTh, 2048, 0,
                nullptr, 0, 0, nullptr, 0, 0,
                out + (size_t)b * 2048 * 1024, 1024, b_out, 2048);
        }
    }
}

// Round 13
// 293.462 us; speedup vs baseline: 1.0575x; 1.0018x over previous
//
#include <hip/hip_runtime.h>
#include <math.h>

#define DIMX 1024
#define QKD  128
#define HIDD 2048
#define BATCH 4
#define SEQ  2048

typedef __bf16 bf16;
typedef __bf16 bf16x8 __attribute__((ext_vector_type(8)));
typedef __bf16 bf16x4v __attribute__((ext_vector_type(4)));
typedef float f32x4 __attribute__((ext_vector_type(4)));

__device__ __forceinline__ float siluf(float v) { return v / (1.f + expf(-v)); }
__device__ __forceinline__ void splitf(float x, bf16& h, bf16& l) {
    h = (bf16)x;
    l = (bf16)(x - (float)h);
}
__device__ __forceinline__ f32x4 mfma16(bf16x8 a, bf16x8 b, f32x4 c) {
    return __builtin_amdgcn_mfma_f32_16x16x32_bf16(a, b, c, 0, 0, 0);
}

typedef __attribute__((address_space(1))) const void cg_void;
typedef __attribute__((address_space(3))) void lds_void_t;
__device__ __forceinline__ void gload16(const bf16* g, bf16* l) {
    __builtin_amdgcn_global_load_lds((cg_void*)g, (lds_void_t*)l, 16, 0, 0);
}

template<int N> __device__ __forceinline__ void wait_vm() {
    if constexpr (N == 0)  asm volatile("s_waitcnt vmcnt(0)" ::: "memory");
    if constexpr (N == 3)  asm volatile("s_waitcnt vmcnt(3)" ::: "memory");
    if constexpr (N == 4)  asm volatile("s_waitcnt vmcnt(4)" ::: "memory");
    if constexpr (N == 6)  asm volatile("s_waitcnt vmcnt(6)" ::: "memory");
    if constexpr (N == 8)  asm volatile("s_waitcnt vmcnt(8)" ::: "memory");
}

#define SB0 __builtin_amdgcn_sched_barrier(0)

// -------------------- LayerNorm -> split bf16 hi/lo --------------------
__global__ __launch_bounds__(256) void ln_split(const float* __restrict__ x,
                                                const float* __restrict__ scale,
                                                const float* __restrict__ bias,
                                                bf16* __restrict__ xh,
                                                bf16* __restrict__ xl) {
    const int row = blockIdx.x;
    const float4 v = reinterpret_cast<const float4*>(x + (size_t)row * DIMX)[threadIdx.x];
    float s  = v.x + v.y + v.z + v.w;
    float ss = v.x * v.x + v.y * v.y + v.z * v.z + v.w * v.w;
    #pragma unroll
    for (int off = 32; off; off >>= 1) {
        s  += __shfl_down(s, off);
        ss += __shfl_down(ss, off);
    }
    __shared__ float ls[4], lss[4];
    const int wid = threadIdx.x >> 6, lane = threadIdx.x & 63;
    if (lane == 0) { ls[wid] = s; lss[wid] = ss; }
    __syncthreads();
    if (threadIdx.x == 0) {
        float a = ls[0] + ls[1] + ls[2] + ls[3];
        float b = lss[0] + lss[1] + lss[2] + lss[3];
        float mu  = a / DIMX;
        float var = b / DIMX - mu * mu;
        ls[0]  = mu;
        lss[0] = rsqrtf(var + 1e-5f);
    }
    __syncthreads();
    const float mu = ls[0], rs = lss[0];
    const float4 sc = reinterpret_cast<const float4*>(scale)[threadIdx.x];
    const float4 bi = reinterpret_cast<const float4*>(bias)[threadIdx.x];
    float o[4];
    o[0] = (v.x - mu) * rs * sc.x + bi.x;
    o[1] = (v.y - mu) * rs * sc.y + bi.y;
    o[2] = (v.z - mu) * rs * sc.z + bi.z;
    o[3] = (v.w - mu) * rs * sc.w + bi.w;
    bf16x4v h, l;
    #pragma unroll
    for (int i = 0; i < 4; ++i) { bf16 hh, ll; splitf(o[i], hh, ll); h[i] = hh; l[i] = ll; }
    *reinterpret_cast<bf16x4v*>(xh + (size_t)row * DIMX + threadIdx.x * 4) = h;
    *reinterpret_cast<bf16x4v*>(xl + (size_t)row * DIMX + threadIdx.x * 4) = l;
}

// ------------- transpose + split: W [K][N] fp32 -> T[N][K] bf16 hi(/lo) -------------
__global__ __launch_bounds__(256) void wsplitT(const float* __restrict__ W, int K, int N,
                                               bf16* __restrict__ Th, bf16* __restrict__ Tl) {
    __shared__ float tile[32][33];
    const int bx = blockIdx.x * 32;   // N dir
    const int by = blockIdx.y * 32;   // K dir
    const int tx = threadIdx.x & 31, ty = threadIdx.x >> 5;
    #pragma unroll
    for (int r = 0; r < 32; r += 8)
        tile[ty + r][tx] = W[(size_t)(by + ty + r) * N + bx + tx];
    __syncthreads();
    #pragma unroll
    for (int r = 0; r < 32; r += 8) {
        const float v = tile[tx][ty + r];
        bf16 h, l; splitf(v, h, l);
        Th[(size_t)(bx + ty + r) * K + by + tx] = h;
        if (Tl) Tl[(size_t)(bx + ty + r) * K + by + tx] = l;
    }
}

// =====================================================================
// gmm2: ring-buffered MFMA GEMM (round-9 proven, single-barrier loop).
// BM=256, BK=32, 512 threads (8 waves 2Mx4N), 4-deep LDS ring.
// Loop: [wait_vm(2L|L|0); barrier; ds_read(t); lgkm0; stage(t+3); MFMA(t)].
// WAR: stage(t+3) overwrites buf[(t-1)&3]; all iter-(t-1) reads completed
// before any wave passed barrier t.  RAW: wait_vm(2L) retires tile t.
// Epilogues (ALL natural row-major stores -- no transposed writes):
// EPI 5 (hid vT half, FLIPPED): rows=n (A=WhT[0:2048]); O[n][m]=silu(acc+e0[n])
// EPI 6 (hid gate half):        rows=m; O[m][n']=silu(acc+e0[n'])
// EPI 3 (av):  y[m][n] = acc * G[m][n]  (gate read row-major, coalesced)
// EPI 4 (out): F[m][n] = acc + e0[n]  fp32
// =====================================================================
template<int EPI, int BN>
__global__ __launch_bounds__(512) void gmm2(
    const bf16* __restrict__ A, int lda, long long sA,
    const bf16* __restrict__ B, int ldb, long long sB,
    bf16* __restrict__ O, int ldo, long long sO,
    bf16* __restrict__ G, int ldg, long long sG,
    float* __restrict__ F, int ldf,
    const float* __restrict__ e0,
    int K) {

    constexpr int BM = 256, BK = 32;
    constexpr int AE = BM * BK;
    constexpr int BE = BN * BK;
    constexpr int CHA = AE / (512 * 8);
    constexpr int CHB = BE / (512 * 8);
    constexpr int L = CHA + CHB;
    constexpr int WN = BN / 4;
    constexpr int MI = 8, NI = WN / 16;

    __shared__ __align__(16) bf16 lds[4 * (AE + BE)];

    const int z = blockIdx.z;
    A += (size_t)sA * z;
    B += (size_t)sB * z;
    bf16* Oz = O ? O + (size_t)sO * z : nullptr;
    bf16* Gz = G ? G + (size_t)sG * z : nullptr;

    const int tid = threadIdx.x;
    const int l = tid & 63, w = tid >> 6;
    const int wr = w >> 2, wc = w & 3;
    const int lr = l & 15, ls4 = l >> 4;
    const int bm = blockIdx.y * BM, bn = blockIdx.x * BN;

    const bf16* aptr[CHA];
    #pragma unroll
    for (int c = 0; c < CHA; ++c) {
        const int flat = c * 512 + tid;
        const int row = flat >> 2;
        const int slot = (flat & 3) ^ ((row >> 1) & 3);
        aptr[c] = A + (size_t)(bm + row) * lda + slot * 8;
    }
    const bf16* bptr[CHB];
    #pragma unroll
    for (int c = 0; c < CHB; ++c) {
        const int flat = c * 512 + tid;
        const int row = flat >> 2;
        const int slot = (flat & 3) ^ ((row >> 1) & 3);
        bptr[c] = B + (size_t)(bn + row) * ldb + slot * 8;
    }

    int aoff[MI], boff[NI];
    #pragma unroll
    for (int i = 0; i < MI; ++i) {
        const int row = wr * 128 + i * 16 + lr;
        aoff[i] = row * BK + (ls4 ^ ((row >> 1) & 3)) * 8;
    }
    #pragma unroll
    for (int j = 0; j < NI; ++j) {
        const int row = wc * WN + j * 16 + lr;
        boff[j] = row * BK + (ls4 ^ ((row >> 1) & 3)) * 8;
    }

    const int NT = K / BK;
    f32x4 acc[MI][NI] = {};

    auto stage = [&](int tile) {
        const int buf = tile & 3;
        bf16* ab = lds + buf * (AE + BE);
        bf16* bb = ab + AE;
        #pragma unroll
        for (int c = 0; c < CHA; ++c)
            gload16(aptr[c] + tile * BK, ab + (c * 512 + w * 64) * 8);
        #pragma unroll
        for (int c = 0; c < CHB; ++c)
            gload16(bptr[c] + tile * BK, bb + (c * 512 + w * 64) * 8);
    };

    stage(0); SB0;
    stage(1); SB0;
    stage(2); SB0;

    for (int t = 0; t < NT; ++t) {
        const int ahead = NT - 1 - t;
        if (ahead >= 2)      wait_vm<2 * L>();   // tiles t+1,t+2 may be in flight
        else if (ahead == 1) wait_vm<L>();
        else                 wait_vm<0>();
        __builtin_amdgcn_s_barrier();            // all waves' tile-t landed
        SB0;

        const int buf = t & 3;
        const bf16* ab = lds + buf * (AE + BE);
        const bf16* bb = ab + AE;
        bf16x8 bfr[NI], afr[MI];
        #pragma unroll
        for (int j = 0; j < NI; ++j)
            bfr[j] = *reinterpret_cast<const bf16x8*>(&bb[boff[j]]);
        #pragma unroll
        for (int i = 0; i < MI; ++i)
            afr[i] = *reinterpret_cast<const bf16x8*>(&ab[aoff[i]]);
        asm volatile("s_waitcnt lgkmcnt(0)" ::: "memory");
        SB0;
        if (t + 3 < NT) { stage(t + 3); }        // overwrites buf[(t-1)&3]: safe
        SB0;
        __builtin_amdgcn_s_setprio(1);
        #pragma unroll
        for (int i = 0; i < MI; ++i)
            #pragma unroll
            for (int j = 0; j < NI; ++j)
                acc[i][j] = mfma16(afr[i], bfr[j], acc[i][j]);
        __builtin_amdgcn_s_setprio(0);
        SB0;
    }

    #pragma unroll
    for (int i = 0; i < MI; ++i) {
        const int mf = bm + wr * 128 + i * 16 + ls4 * 4;
        #pragma unroll
        for (int j = 0; j < NI; ++j) {
            const int nn = bn + wc * WN + j * 16 + lr;
            const f32x4 a = acc[i][j];
            if constexpr (EPI == 5) {
                // hid vT half (flipped): rows=n, cols=m; bias by ROW
                #pragma unroll
                for (int r = 0; r < 4; ++r) {
                    const float s = siluf(a[r] + e0[mf + r]);
                    Oz[(size_t)(mf + r) * ldo + nn] = (bf16)s;
                }
            } else if constexpr (EPI == 6) {
                // hid gate half (natural): rows=m, cols=n'; bias by COL
                #pragma unroll
                for (int r = 0; r < 4; ++r) {
                    const float s = siluf(a[r] + e0[nn]);
                    Oz[(size_t)(mf + r) * ldo + nn] = (bf16)s;
                }
            } else if constexpr (EPI == 3) {
                // av: y[m][n] = acc * gate[m][n]  (row-major gate read)
                #pragma unroll
                for (int r = 0; r < 4; ++r) {
                    const float g = (float)Gz[(size_t)(mf + r) * ldg + nn];
                    Oz[(size_t)(mf + r) * ldo + nn] = (bf16)(a[r] * g);
                }
            } else {
                #pragma unroll
                for (int r = 0; r < 4; ++r)
                    F[(size_t)(mf + r) * ldf + nn] = a[r] + e0[nn];
            }
        }
    }
}

// ---------------- round-4 2-barrier kernel: qk (EPI1) and sim (EPI2) ----------
template<int EPI, bool SPLIT, int MI, int NI>
__global__ __launch_bounds__(256) void gmm(
    const bf16* __restrict__ Ah, const bf16* __restrict__ Al, int lda, long long sA,
    const bf16* __restrict__ Bh, const bf16* __restrict__ Bl, int ldb, long long sB,
    bf16* __restrict__ O, int ldo, long long sO,
    bf16* __restrict__ O2, bf16* __restrict__ O3, bf16* __restrict__ O4,
    const float* __restrict__ e0, const float* __restrict__ e1, const float* __restrict__ e2,
    int K, float scale) {

    constexpr int TM = MI * 32, TN = NI * 32;
    constexpr int CHA = TM / 64, CHB = TN / 64;
    __shared__ __align__(16) bf16 As[TM * 32];
    __shared__ __align__(16) bf16 Bs[TN * 32];

    const int z = blockIdx.z;
    Ah += (size_t)sA * z;
    if (SPLIT) Al += (size_t)sA * z;
    Bh += (size_t)sB * z;
    if (SPLIT) Bl += (size_t)sB * z;
    if (O) O += (size_t)sO * z;

    const int t = threadIdx.x;
    const int l = t & 63, w = t >> 6;
    const int wr = w >> 1, wc = w & 1;
    const int lr = l & 15, ls = l >> 4;
    const int bm = blockIdx.y * TM, bn = blockIdx.x * TN;

    f32x4 acc[MI][NI] = {};
    const int KT = SPLIT ? 3 * K : K;

    for (int k0 = 0; k0 < KT; k0 += 32) {
        const bf16 *pA, *pB;
        int kin;
        if constexpr (SPLIT) {
            if (k0 < K)          { pA = Ah; pB = Bh; kin = k0; }
            else if (k0 < 2 * K) { pA = Al; pB = Bh; kin = k0 - K; }
            else                 { pA = Ah; pB = Bl; kin = k0 - 2 * K; }
        } else { pA = Ah; pB = Bh; kin = k0; }

        #pragma unroll
        for (int c = 0; c < CHA; ++c) {
            const int idx = c * 256 + w * 64 + l;
            const int row = idx >> 2;
            const int sg = (idx & 3) ^ ((row >> 1) & 3);
            gload16(pA + (size_t)(bm + row) * lda + kin + sg * 8,
                    As + (size_t)(c * 256 + w * 64) * 8);
        }
        #pragma unroll
        for (int c = 0; c < CHB; ++c) {
            const int idx = c * 256 + w * 64 + l;
            const int row = idx >> 2;
            const int sg = (idx & 3) ^ ((row >> 1) & 3);
            gload16(pB + (size_t)(bn + row) * ldb + kin + sg * 8,
                    Bs + (size_t)(c * 256 + w * 64) * 8);
        }
        __syncthreads();

        bf16x8 bfr[NI];
        #pragma unroll
        for (int j = 0; j < NI; ++j) {
            const int row = wc * (NI * 16) + j * 16 + lr;
            const int sl = ls ^ ((row >> 1) & 3);
            bfr[j] = *reinterpret_cast<const bf16x8*>(&Bs[row * 32 + sl * 8]);
        }
        #pragma unroll
        for (int i = 0; i < MI; ++i) {
            const int row = wr * (MI * 16) + i * 16 + lr;
            const int sl = ls ^ ((row >> 1) & 3);
            const bf16x8 af = *reinterpret_cast<const bf16x8*>(&As[row * 32 + sl * 8]);
            #pragma unroll
            for (int j = 0; j < NI; ++j)
                acc[i][j] = mfma16(af, bfr[j], acc[i][j]);
        }
        __syncthreads();
    }

    #pragma unroll
    for (int i = 0; i < MI; ++i) {
        const int mf = bm + wr * (MI * 16) + i * 16 + ls * 4;
        #pragma unroll
        for (int j = 0; j < NI; ++j) {
            const int nn = bn + wc * (NI * 16) + j * 16 + lr;
            const f32x4 a = acc[i][j];
            if constexpr (EPI == 1) {
                #pragma unroll
                for (int r = 0; r < 4; ++r) {
                    const float s = siluf(a[r] + e0[nn]);
                    const float q = s * e1[nn] + e2[nn];
                    const float k = s * e1[QKD + nn] + e2[QKD + nn];
                    bf16 h, lo;
                    splitf(q, h, lo);
                    O[(size_t)(mf + r) * ldo + nn] = h;  O2[(size_t)(mf + r) * ldo + nn] = lo;
                    splitf(k, h, lo);
                    O3[(size_t)(mf + r) * ldo + nn] = h; O4[(size_t)(mf + r) * ldo + nn] = lo;
                }
            } else if constexpr (EPI == 2) {
                #pragma unroll
                for (int r = 0; r < 4; ++r) {
                    const float tv = a[r] * scale;
                    const float p = tv > 0.f ? tv * tv : 0.f;
                    O[(size_t)(mf + r) * ldo + nn] = (bf16)p;
                }
            }
        }
    }
}

extern "C" void kernel_launch(void* const* d_in, const int* in_sizes, int n_in,
                              void* d_out, int out_size, void* d_ws, size_t ws_size,
                              hipStream_t stream) {
    const float* x        = (const float*)d_in[0];
    const float* ln_scale = (const float*)d_in[1];
    const float* ln_bias  = (const float*)d_in[2];
    const float* W_hidden = (const float*)d_in[3];
    const float* b_hidden = (const float*)d_in[4];
    const float* W_qk     = (const float*)d_in[5];
    const float* b_qk     = (const float*)d_in[6];
    const float* os_w     = (const float*)d_in[7];
    const float* os_b     = (const float*)d_in[8];
    const float* W_out    = (const float*)d_in[9];
    const float* b_out    = (const float*)d_in[10];
    float* out = (float*)d_out;

    // ---- weight prep area ----
    char* p = (char*)d_ws;
    bf16* WhTh  = (bf16*)p; p += (size_t)4096 * 1024 * 2;   // [4096][1024]
    bf16* WqkTh = (bf16*)p; p += (size_t)128 * 1024 * 2;    // [128][1024] hi
    bf16* WqkTl = (bf16*)p; p += (size_t)128 * 1024 * 2;    // lo
    bf16* WoTh  = (bf16*)p; p += (size_t)1024 * 2048 * 2;   // [1024][2048]

    wsplitT<<<dim3(4096 / 32, 1024 / 32), 256, 0, stream>>>(W_hidden, 1024, 4096, WhTh, nullptr);
    wsplitT<<<dim3(128 / 32, 1024 / 32), 256, 0, stream>>>(W_qk, 1024, 128, WqkTh, WqkTl);
    wsplitT<<<dim3(1024 / 32, 2048 / 32), 256, 0, stream>>>(W_out, 2048, 1024, WoTh, nullptr);

    const size_t used = (size_t)(p - (char*)d_ws);
    const size_t qkB   = (size_t)4 * 8192 * 128 * 2;
    const size_t vTB   = (size_t)2048 * 8192 * 2;
    const size_t gateB = (size_t)8192 * 2048 * 2;
    const size_t attnB = (size_t)4 * 2048 * 2048 * 2;
    const size_t yB    = (size_t)8192 * 2048 * 2;
    const bool allb = (ws_size >= used + qkB + vTB + gateB + attnB + yB + (1u << 20));

    if (allb) {
        bf16* xh = (bf16*)out;                      // d_out doubles as xn hi/lo
        bf16* xl = xh + (size_t)8192 * 1024;
        bf16* qh   = (bf16*)p; p += (size_t)8192 * 128 * 2;
        bf16* ql   = (bf16*)p; p += (size_t)8192 * 128 * 2;
        bf16* kh   = (bf16*)p; p += (size_t)8192 * 128 * 2;
        bf16* kl   = (bf16*)p; p += (size_t)8192 * 128 * 2;
        bf16* vT   = (bf16*)p; p += vTB;            // [2048][8192]  (n, m)
        bf16* gate = (bf16*)p; p += gateB;          // [8192][2048]  (m, n')  ROW-MAJOR
        bf16* attn = (bf16*)p; p += attnB;          // [4][2048][2048]
        bf16* y    = (bf16*)p; p += yB;             // [8192][2048]

        ln_split<<<8192, 256, 0, stream>>>(x, ln_scale, ln_bias, xh, xl);

        // hid-v (FLIPPED): vT[2048][8192] = silu(WhT[0:2048] . xh^T + b_v)
        gmm2<5, 256><<<dim3(8192 / 256, 2048 / 256), 512, 0, stream>>>(
            WhTh, 1024, 0, xh, 1024, 0,
            vT, 8192, 0, nullptr, 0, 0,
            nullptr, 0, b_hidden, 1024);

        // hid-gate (natural): gate[8192][2048] = silu(xh . Wh[:,2048:] + b_g)
        gmm2<6, 256><<<dim3(2048 / 256, 8192 / 256), 512, 0, stream>>>(
            xh, 1024, 0, WhTh + (size_t)2048 * 1024, 1024, 0,
            gate, 2048, 0, nullptr, 0, 0,
            nullptr, 0, b_hidden + HIDD, 1024);

        // qk (split): [8192 x 128] -> q,k hi/lo
        gmm<1, true, 2, 2><<<dim3(128 / 64, 8192 / 64), 256, 0, stream>>>(
            xh, xl, 1024, 0, WqkTh, WqkTl, 1024, 0,
            qh, 128, 0, ql, kh, kl,
            b_qk, os_w, os_b, 1024, 0.f);

        // sim (split): per-batch [2048 x 2048]
        gmm<2, true, 4, 4><<<dim3(16, 16, 4), 256, 0, stream>>>(
            qh, ql, 128, (long long)2048 * 128, kh, kl, 128, (long long)2048 * 128,
            attn, 2048, (long long)2048 * 2048, nullptr, nullptr, nullptr,
            nullptr, nullptr, nullptr, 128, 1.0f / SEQ);

        // av: y[m][n] = (attn @ v) * gate[m][n]   per batch
        gmm2<3, 256><<<dim3(2048 / 256, 2048 / 256, 4), 512, 0, stream>>>(
            attn, 2048, (long long)2048 * 2048, vT, 8192, 2048,
            y, 2048, (long long)2048 * 2048, gate, 2048, (long long)2048 * 2048,
            nullptr, 0, nullptr, 2048);

        // out: [8192 x 1024] fp32 -> d_out
        gmm2<4, 128><<<dim3(1024 / 128, 8192 / 256), 512, 0, stream>>>(
            y, 2048, 0, WoTh, 2048, 0,
            nullptr, 0, 0, nullptr, 0, 0,
            out, 1024, b_out, 2048);
    } else {
        // ---------------- per-batch fallback ----------------
        bf16* xh = (bf16*)p; p += (size_t)8192 * 1024 * 2;
        bf16* xl = (bf16*)p; p += (size_t)8192 * 1024 * 2;
        bf16* qh   = (bf16*)p; p += (size_t)2048 * 128 * 2;
        bf16* ql   = (bf16*)p; p += (size_t)2048 * 128 * 2;
        bf16* kh   = (bf16*)p; p += (size_t)2048 * 128 * 2;
        bf16* kl   = (bf16*)p; p += (size_t)2048 * 128 * 2;
        bf16* vT   = (bf16*)p; p += (size_t)2048 * 2048 * 2;   // [2048 n][2048 m]
        bf16* gate = (bf16*)p; p += (size_t)2048 * 2048 * 2;   // [2048 m][2048 n']
        bf16* attn = (bf16*)p; p += (size_t)2048 * 2048 * 2;
        bf16* y    = (bf16*)p; p += (size_t)2048 * 2048 * 2;

        ln_split<<<8192, 256, 0, stream>>>(x, ln_scale, ln_bias, xh, xl);

        for (int b = 0; b < BATCH; ++b) {
            const bf16* xhb = xh + (size_t)b * 2048 * 1024;
            const bf16* xlb = xl + (size_t)b * 2048 * 1024;

            // hid-v flipped: vT[2048][2048]
            gmm2<5, 256><<<dim3(2048 / 256, 2048 / 256), 512, 0, stream>>>(
                WhTh, 1024, 0, xhb, 1024, 0,
                vT, 2048, 0, nullptr, 0, 0,
                nullptr, 0, b_hidden, 1024);

            // hid-gate natural: gate[2048][2048]
            gmm2<6, 256><<<dim3(2048 / 256, 2048 / 256), 512, 0, stream>>>(
                xhb, 1024, 0, WhTh + (size_t)2048 * 1024, 1024, 0,
                gate, 2048, 0, nullptr, 0, 0,
                nullptr, 0, b_hidden + HIDD, 1024);

            gmm<1, true, 2, 2><<<dim3(128 / 64, 2048 / 64), 256, 0, stream>>>(
                xhb, xlb, 1024, 0, WqkTh, WqkTl, 1024, 0,
                qh, 128, 0, ql, kh, kl,
                b_qk, os_w, os_b, 1024, 0.f);

            gmm<2, true, 4, 4><<<dim3(16, 16, 1), 256, 0, stream>>>(
                qh, ql, 128, 0, kh, kl, 128, 0,
                attn, 2048, 0, nullptr, nullptr, nullptr,
                nullptr, nullptr, nullptr, 128, 1.0f / SEQ);

            gmm2<3, 256><<<dim3(2048 / 256, 2048 / 256, 1), 512, 0, stream>>>(
                attn, 2048, 0, vT, 2048, 0,
                y, 2048, 0, gate, 2048, 0,
                nullptr, 0, nullptr, 2048);

            gmm2<4, 128><<<dim3(1024 / 128, 2048 / 256), 512, 0, stream>>>(
                y, 2048, 0, WoTh, 2048, 0,
                nullptr, 0, 0, nullptr, 0, 0,
                out + (size_t)b * 2048 * 1024, 1024, b_out, 2048);
        }
    }
}